// Round 5
// baseline (1091.440 us; speedup 1.0000x reference)
//
#include <hip/hip_runtime.h>

// LSTM B=512 T=1024 H=150 I=1 + Linear(150->1) + sigmoid.
// 32 blocks x 768 threads (12 waves). Block owns 16 sequences.
// M = 640 virtual rows, vrow = 4*cell+gate (cell-major), 38 MFMA tiles of 16;
//   vrow 600 carries W_out. K = 160: k<150 = h (f16 LDS, double-buffered),
//   k=150 = 1.0 (bias), k=151 = x_t. Weights pre-scaled by -log2e / +2log2e
//   so pointwise = 5 exp2 + 2 rcp per cell.
// ROUND-5 CHANGE: skewed 2-barrier schedule to break the per-step convoy
//   (r1/r3/r4 all pinned at 1032us regardless of waves/VGPR => phase
//   serialization, not occupancy, is the wall).
//   early = K-chunks s0,s1 (cells 0-63), tiles 0-15; late = s2..s4, tiles 16-37.
//   Step: mfma(s0,s1; prefetched) -> read bf234 -> mfma(s2..4) -> trans early
//   -> bar1 -> prefetch next bf01 (overlaps trans late) -> trans late -> bar2.

typedef _Float16 half8 __attribute__((ext_vector_type(8)));
typedef float f32x4 __attribute__((ext_vector_type(4)));

#define LOG2E 1.44269504088896340736f
#define TWOLOG2E 2.88539008177792681472f

__global__
__attribute__((amdgpu_flat_work_group_size(768, 768), amdgpu_waves_per_eu(3, 3)))
void lstm_kernel(
    const float* __restrict__ x,      // [512][1024]
    const float* __restrict__ W_ih,   // [600]
    const float* __restrict__ W_hh,   // [600][150]
    const float* __restrict__ b_ih,   // [600]
    const float* __restrict__ b_hh,   // [600]
    const float* __restrict__ W_out,  // [150]
    const float* __restrict__ b_out,  // [1]
    float* __restrict__ out)          // [512][1024]
{
  const int tid  = threadIdx.x;
  const int wid  = tid >> 6;
  const int lane = tid & 63;
  const int q    = lane >> 4;   // k-subchunk for A/B frags; cell offset for D
  const int b    = lane & 15;   // batch col (B/D); A-frag row m
  const int bid  = blockIdx.x;

  __shared__ __align__(16) _Float16 hbuf[2][16][168];
  __shared__ _Float16 xlds[16][1032];

  // ---- prologue: zero hbuf, stage x as f16 ----
  for (int i = tid; i < 2*16*168; i += 768)
    (&hbuf[0][0][0])[i] = (_Float16)0.0f;
  {
    const float4* x4 = (const float4*)(x + (size_t)bid * 16 * 1024);
    for (int i = tid; i < 16*256; i += 768) {
      int row = i >> 8, c4 = i & 255;
      float4 v = x4[row*256 + c4];
      xlds[row][c4*4+0] = (_Float16)v.x;
      xlds[row][c4*4+1] = (_Float16)v.y;
      xlds[row][c4*4+2] = (_Float16)v.z;
      xlds[row][c4*4+3] = (_Float16)v.w;
    }
  }
  __syncthreads();
  if (tid < 32) hbuf[tid>>4][tid&15][150] = (_Float16)1.0f;  // bias column
  if (tid < 16) hbuf[0][tid][151] = xlds[tid][0];            // x_0
  __syncthreads();

  // ---- tile ownership: slots 0,1 = early (tiles 0-15), 2,3 = late (16-37) ----
  int tiles[4];
  tiles[0] = wid;        // always valid
  tiles[1] = 12 + wid;   // valid wid<4
  tiles[2] = 16 + wid;   // always valid
  tiles[3] = 28 + wid;   // valid wid<10
  const bool v1 = (wid < 4), v3 = (wid < 10);

  // ---- weight fragments (A operand): up to 4 tiles x 5 K-chunks = 80 VGPR ----
  const float bo = b_out[0];
  half8 wf[4][5];
#pragma unroll
  for (int tl = 0; tl < 4; ++tl) {
#pragma unroll
    for (int s = 0; s < 5; ++s) wf[tl][s] = (half8)(_Float16)0.0f;
    const bool vv = (tl == 0) || (tl == 2) || (tl == 1 && v1) || (tl == 3 && v3);
    if (vv) {
      const int tg   = tiles[tl];
      const int vrow = tg*16 + b;     // A-frag: m = lane&15
      const int cell = vrow >> 2, gate = vrow & 3;
      const float alpha = (gate == 2) ? TWOLOG2E : -LOG2E;
#pragma unroll
      for (int s = 0; s < 5; ++s) {
        half8 v;
#pragma unroll
        for (int j = 0; j < 8; ++j) {
          const int k = s*32 + q*8 + j;  // same (q,j)->k map as B frags
          float w = 0.0f;
          if (vrow == 600) {             // out row
            if (k < 150)       w = -LOG2E * W_out[k];
            else if (k == 150) w = -LOG2E * bo;
          } else if (cell < 150) {
            const int orow = gate*150 + cell;
            if (k < 150)       w = alpha * W_hh[orow*150 + k];
            else if (k == 150) w = alpha * (b_ih[orow] + b_hh[orow]);
            else if (k == 151) w = alpha * W_ih[orow];
          }
          v[j] = (_Float16)w;
        }
        wf[tl][s] = v;
      }
    }
  }

  float cst[4] = {0.f, 0.f, 0.f, 0.f};
  const bool is_x   = (wid == 11) && (q == 3);
  const bool is_out = (wid == 9)  && (q == 2);  // vrow 600 = tile 37 -> slot 3, reg 0
  float* outp = out + ((size_t)bid*16 + b) * 1024;

  // prefetch early chunks of buf 0 (h(-1) early cells = 0)
  half8 bf01_0 = *(const half8*)&hbuf[0][b][q*8];
  half8 bf01_1 = *(const half8*)&hbuf[0][b][32 + q*8];

  int cur = 0;
  for (int t = 0; t <= 1024; ++t) {
    _Float16 xv = (_Float16)0.0f;
    if (is_x && t < 1023) xv = xlds[b][t+1];

    // ---- phase 1: MFMA on prefetched early chunks ----
    f32x4 acc[4];
#pragma unroll
    for (int tl = 0; tl < 4; ++tl) {
      f32x4 a = {0.f, 0.f, 0.f, 0.f};
      a = __builtin_amdgcn_mfma_f32_16x16x32_f16(wf[tl][0], bf01_0, a, 0, 0, 0);
      a = __builtin_amdgcn_mfma_f32_16x16x32_f16(wf[tl][1], bf01_1, a, 0, 0, 0);
      acc[tl] = a;
    }

    // ---- phase 2: read late chunks (latency hides under phase-1 MFMA) ----
    half8 bf2 = *(const half8*)&hbuf[cur][b][64  + q*8];
    half8 bf3 = *(const half8*)&hbuf[cur][b][96  + q*8];
    half8 bf4 = *(const half8*)&hbuf[cur][b][128 + q*8];
#pragma unroll
    for (int tl = 0; tl < 4; ++tl) {
      acc[tl] = __builtin_amdgcn_mfma_f32_16x16x32_f16(wf[tl][2], bf2, acc[tl], 0, 0, 0);
      acc[tl] = __builtin_amdgcn_mfma_f32_16x16x32_f16(wf[tl][3], bf3, acc[tl], 0, 0, 0);
      acc[tl] = __builtin_amdgcn_mfma_f32_16x16x32_f16(wf[tl][4], bf4, acc[tl], 0, 0, 0);
    }

    // out_{t-1} = sigmoid(Wout.h_{t-1} + b_out); acc pre-scaled by -log2e
    if (is_out && t >= 1)
      outp[t-1] = __builtin_amdgcn_rcpf(1.0f + __builtin_amdgcn_exp2f(acc[3][0]));
    if (t == 1024) break;

    const int nxt = cur ^ 1;

    // ---- trans early tiles (slots 0,1): cells 0-63 of h(t) ----
#pragma unroll
    for (int tl = 0; tl < 2; ++tl) {
      if (tl == 0 || v1) {
        const int cellg = tiles[tl]*4 + q;      // < 64 always
        const float ei = __builtin_amdgcn_exp2f(acc[tl][0]);
        const float ef = __builtin_amdgcn_exp2f(acc[tl][1]);
        const float eg = __builtin_amdgcn_exp2f(acc[tl][2]);
        const float eo = __builtin_amdgcn_exp2f(acc[tl][3]);
        const float A  = 1.0f + ei;
        const float F  = 1.0f + ef;
        const float G1 = eg + 1.0f;
        const float Gm = eg - 1.0f;
        const float AG = A * G1;
        const float num = fmaf(cst[tl], AG, Gm * F);
        const float cn  = num * __builtin_amdgcn_rcpf(F * AG);
        cst[tl] = cn;
        const float ec = __builtin_amdgcn_exp2f(TWOLOG2E * cn);
        const float h  = (ec - 1.0f) *
                         __builtin_amdgcn_rcpf((1.0f + eo) * (ec + 1.0f));
        hbuf[nxt][b][cellg] = (_Float16)h;
      }
    }
    __syncthreads();   // bar1: early cells of h(t) visible

    // ---- prefetch next step's early chunks (overlaps trans-late below) ----
    bf01_0 = *(const half8*)&hbuf[nxt][b][q*8];
    bf01_1 = *(const half8*)&hbuf[nxt][b][32 + q*8];

    // ---- trans late tiles (slots 2,3): cells 64-149 (+ out row ignored) ----
#pragma unroll
    for (int tl = 2; tl < 4; ++tl) {
      if (tl == 2 || v3) {
        const int cellg = tiles[tl]*4 + q;
        const float ei = __builtin_amdgcn_exp2f(acc[tl][0]);
        const float ef = __builtin_amdgcn_exp2f(acc[tl][1]);
        const float eg = __builtin_amdgcn_exp2f(acc[tl][2]);
        const float eo = __builtin_amdgcn_exp2f(acc[tl][3]);
        const float A  = 1.0f + ei;
        const float F  = 1.0f + ef;
        const float G1 = eg + 1.0f;
        const float Gm = eg - 1.0f;
        const float AG = A * G1;
        const float num = fmaf(cst[tl], AG, Gm * F);
        const float cn  = num * __builtin_amdgcn_rcpf(F * AG);
        cst[tl] = cn;
        const float ec = __builtin_amdgcn_exp2f(TWOLOG2E * cn);
        const float h  = (ec - 1.0f) *
                         __builtin_amdgcn_rcpf((1.0f + eo) * (ec + 1.0f));
        if (cellg < 150) hbuf[nxt][b][cellg] = (_Float16)h;  // skip bias/x/out rows
      }
    }
    if (is_x && t < 1023) hbuf[nxt][b][151] = xv;  // x_{t+1}
    __syncthreads();   // bar2: late cells of h(t) visible
    cur = nxt;
  }
}

extern "C" void kernel_launch(void* const* d_in, const int* in_sizes, int n_in,
                              void* d_out, int out_size, void* d_ws, size_t ws_size,
                              hipStream_t stream) {
  const float* x     = (const float*)d_in[0];
  const float* W_ih  = (const float*)d_in[1];
  const float* W_hh  = (const float*)d_in[2];
  const float* b_ih  = (const float*)d_in[3];
  const float* b_hh  = (const float*)d_in[4];
  const float* W_out = (const float*)d_in[5];
  const float* b_out = (const float*)d_in[6];
  lstm_kernel<<<dim3(32), dim3(768), 0, stream>>>(
      x, W_ih, W_hh, b_ih, b_hh, W_out, b_out, (float*)d_out);
}

// Round 6
// 997.764 us; speedup vs baseline: 1.0939x; 1.0939x over previous
//
#include <hip/hip_runtime.h>

// LSTM B=512 T=1024 H=150 I=1 + Linear(150->1) + sigmoid.
// 32 blocks x 768 threads (12 waves). Block owns 16 sequences.
// M = 640 virtual rows, vrow = 4*cell+gate (cell-major), 38 MFMA tiles of 16;
//   vrow 600 carries W_out. K = 160: k<150 = h (f16 LDS, double-buffered),
//   k=150 = 1.0 (bias), k=151 = x_t. Weights pre-scaled by -log2e / +2log2e
//   so pointwise = 5 exp2 + 2 rcp per cell.
// ROUND-6 CHANGE: LDS padded >80KB (xlds[16][2700], total ~95KB) so only ONE
//   block fits per CU. r1/r3/r4/r5 all ran ~1032us with VGPR_Count 76-124 <
//   the 80-100 VGPRs the weight fragments need: with 44KB LDS two 768-thread
//   blocks fit per CU (6 waves/EU), so the allocator targeted ~85 VGPRs and
//   spilled/sank the weights -> per-step reload from L2 was the invariant
//   wall. 95KB LDS -> 12 waves/CU -> 3 waves/EU -> ~170 VGPR budget ->
//   weights register-resident. Grid was always 1 block/CU at runtime (32
//   blocks, 256 CUs) so the padding costs nothing.

typedef _Float16 half8 __attribute__((ext_vector_type(8)));
typedef float f32x4 __attribute__((ext_vector_type(4)));

#define LOG2E 1.44269504088896340736f
#define TWOLOG2E 2.88539008177792681472f

__global__
__attribute__((amdgpu_flat_work_group_size(768, 768), amdgpu_waves_per_eu(3, 3)))
void lstm_kernel(
    const float* __restrict__ x,      // [512][1024]
    const float* __restrict__ W_ih,   // [600]
    const float* __restrict__ W_hh,   // [600][150]
    const float* __restrict__ b_ih,   // [600]
    const float* __restrict__ b_hh,   // [600]
    const float* __restrict__ W_out,  // [150]
    const float* __restrict__ b_out,  // [1]
    float* __restrict__ out)          // [512][1024]
{
  const int tid  = threadIdx.x;
  const int wid  = tid >> 6;
  const int lane = tid & 63;
  const int q    = lane >> 4;   // k-subchunk for A/B frags; cell offset for D
  const int b    = lane & 15;   // batch col (B/D); A-frag row m
  const int bid  = blockIdx.x;

  // stride 168 f16 = 336 B: b128 panel reads are 2-way on banks (free)
  __shared__ __align__(16) _Float16 hbuf[2][16][168];
  // [16][2700] = 86.4 KB: cols 0-1023 hold x; the rest is occupancy padding
  // (forces 1 block/CU so the register allocator budgets 3 waves/EU).
  __shared__ _Float16 xlds[16][2700];

  // ---- prologue: zero hbuf, stage x as f16 ----
  for (int i = tid; i < 2*16*168; i += 768)
    (&hbuf[0][0][0])[i] = (_Float16)0.0f;
  {
    const float4* x4 = (const float4*)(x + (size_t)bid * 16 * 1024);
    for (int i = tid; i < 16*256; i += 768) {
      int row = i >> 8, c4 = i & 255;
      float4 v = x4[row*256 + c4];
      xlds[row][c4*4+0] = (_Float16)v.x;
      xlds[row][c4*4+1] = (_Float16)v.y;
      xlds[row][c4*4+2] = (_Float16)v.z;
      xlds[row][c4*4+3] = (_Float16)v.w;
    }
  }
  __syncthreads();
  if (tid < 32) hbuf[tid>>4][tid&15][150] = (_Float16)1.0f;  // bias column
  if (tid < 16) hbuf[0][tid][151] = xlds[tid][0];            // x_0
  __syncthreads();

  // ---- tile ownership ----
  const int ntl = (wid == 0 || wid == 5) ? 4 : 3;
  int tiles[4];
  tiles[0] = wid; tiles[1] = 12 + wid; tiles[2] = 24 + wid;
  tiles[3] = (wid == 0) ? 36 : 37;   // only used when ntl==4

  // ---- weight fragments (A operand): up to 4 tiles x 5 K-chunks = 80 VGPR ----
  const float bo = b_out[0];
  half8 wf[4][5];
#pragma unroll
  for (int tl = 0; tl < 4; ++tl) {
#pragma unroll
    for (int s = 0; s < 5; ++s) wf[tl][s] = (half8)(_Float16)0.0f;
    if (tl < ntl) {
      const int tg   = tiles[tl];
      const int vrow = tg*16 + b;     // A-frag: m = lane&15
      const int cell = vrow >> 2, gate = vrow & 3;
      const float alpha = (gate == 2) ? TWOLOG2E : -LOG2E;
#pragma unroll
      for (int s = 0; s < 5; ++s) {
        half8 v;
#pragma unroll
        for (int j = 0; j < 8; ++j) {
          const int k = s*32 + q*8 + j;  // same (q,j)->k map as B frags
          float w = 0.0f;
          if (vrow == 600) {             // out row
            if (k < 150)       w = -LOG2E * W_out[k];
            else if (k == 150) w = -LOG2E * bo;
          } else if (cell < 150) {
            const int orow = gate*150 + cell;
            if (k < 150)       w = alpha * W_hh[orow*150 + k];
            else if (k == 150) w = alpha * (b_ih[orow] + b_hh[orow]);
            else if (k == 151) w = alpha * W_ih[orow];
          }
          v[j] = (_Float16)w;
        }
        wf[tl][s] = v;
      }
    }
  }

  float cst[4] = {0.f, 0.f, 0.f, 0.f};
  const bool is_x   = (wid == 11) && (q == 3);
  const bool is_out = (wid == 5)  && (q == 2);  // vrow 600 -> tile 37 (tl=3), reg 0
  float* outp = out + ((size_t)bid*16 + b) * 1024;

  int cur = 0;
  for (int t = 0; t <= 1024; ++t) {
    _Float16 xv = (_Float16)0.0f;
    if (is_x && t < 1023) xv = xlds[b][t+1];   // issued early, used post-pointwise

    half8 bf[5];
#pragma unroll
    for (int s = 0; s < 5; ++s)
      bf[s] = *(const half8*)&hbuf[cur][b][s*32 + q*8];

    f32x4 acc[4];
#pragma unroll
    for (int tl = 0; tl < 4; ++tl) {
      if (tl < ntl) {
        f32x4 a = {0.f, 0.f, 0.f, 0.f};
#pragma unroll
        for (int s = 0; s < 5; ++s)
          a = __builtin_amdgcn_mfma_f32_16x16x32_f16(wf[tl][s], bf[s], a, 0, 0, 0);
        acc[tl] = a;
      }
    }

    // out_{t-1} = sigmoid(Wout.h_{t-1} + b_out); acc pre-scaled by -log2e
    if (is_out && t >= 1)
      outp[t-1] = __builtin_amdgcn_rcpf(1.0f + __builtin_amdgcn_exp2f(acc[3][0]));
    if (t == 1024) break;

    const int nxt = cur ^ 1;
#pragma unroll
    for (int tl = 0; tl < 4; ++tl) {
      if (tl < ntl) {
        const int cellg = tiles[tl]*4 + q;
        // acc regs: 0=i',1=f',2=g',3=o' (pre-scaled preacts)
        const float ei = __builtin_amdgcn_exp2f(acc[tl][0]);
        const float ef = __builtin_amdgcn_exp2f(acc[tl][1]);
        const float eg = __builtin_amdgcn_exp2f(acc[tl][2]);
        const float eo = __builtin_amdgcn_exp2f(acc[tl][3]);
        const float A  = 1.0f + ei;     // 1/i
        const float F  = 1.0f + ef;     // 1/f
        const float G1 = eg + 1.0f;
        const float Gm = eg - 1.0f;     // g = Gm/G1
        const float AG = A * G1;
        const float num = fmaf(cst[tl], AG, Gm * F);     // c*A*G1 + Gm*F
        const float cn  = num * __builtin_amdgcn_rcpf(F * AG);
        cst[tl] = cn;
        const float ec = __builtin_amdgcn_exp2f(TWOLOG2E * cn);
        const float h  = (ec - 1.0f) *
                         __builtin_amdgcn_rcpf((1.0f + eo) * (ec + 1.0f)); // o*tanh(c)
        if (cellg < 150) hbuf[nxt][b][cellg] = (_Float16)h;
      }
    }
    if (is_x && t < 1023) hbuf[nxt][b][151] = xv;  // x_{t+1}
    __syncthreads();
    cur = nxt;
  }
}

extern "C" void kernel_launch(void* const* d_in, const int* in_sizes, int n_in,
                              void* d_out, int out_size, void* d_ws, size_t ws_size,
                              hipStream_t stream) {
  const float* x     = (const float*)d_in[0];
  const float* W_ih  = (const float*)d_in[1];
  const float* W_hh  = (const float*)d_in[2];
  const float* b_ih  = (const float*)d_in[3];
  const float* b_hh  = (const float*)d_in[4];
  const float* W_out = (const float*)d_in[5];
  const float* b_out = (const float*)d_in[6];
  lstm_kernel<<<dim3(32), dim3(768), 0, stream>>>(
      x, W_ih, W_hh, b_ih, b_hh, W_out, b_out, (float*)d_out);
}